// Round 5
// baseline (301.980 us; speedup 1.0000x reference)
//
#include <hip/hip_runtime.h>
#include <hip/hip_bf16.h>
#include <stdint.h>

#define B_N 4
#define SEQ 2048
#define DMODEL 1024
#define NHEAD 16
#define HDIM 64
#define BHEADS (B_N * NHEAD)     // 64
#define MROWS (B_N * SEQ)        // 8192

typedef short bf16x8_t __attribute__((ext_vector_type(8)));
typedef float f32x4_t __attribute__((ext_vector_type(4)));

static __device__ __forceinline__ unsigned short f2bf(float f) {
  __hip_bfloat16 h = __float2bfloat16(f);
  return __builtin_bit_cast(unsigned short, h);
}

#define GLDS16(gp, lp)                                                        \
  __builtin_amdgcn_global_load_lds(                                           \
      (const __attribute__((address_space(1))) unsigned int*)(gp),            \
      (__attribute__((address_space(3))) unsigned int*)(lp), 16, 0, 0)

// ---------------- fused fp32 -> bf16 cast (x + all 4 weights) -------------
#define XE4 2097152   // MROWS*DMODEL/4
#define WE4 262144    // DMODEL*DMODEL/4
__global__ void cast_all(const float* __restrict__ x,
                         const float* __restrict__ Wq,
                         const float* __restrict__ Wk,
                         const float* __restrict__ Wv,
                         const float* __restrict__ Wo,
                         unsigned short* __restrict__ xb,
                         unsigned short* __restrict__ wb) {
  int i = blockIdx.x * blockDim.x + threadIdx.x;
  const float* src;
  unsigned short* dst;
  int off;
  float scale = 1.0f;
  if (i < XE4) {
    src = x; dst = xb; off = i;
  } else {
    int j = i - XE4;
    int mat = j >> 18;                       // WE4 = 2^18
    off = j & (WE4 - 1);
    src = (mat == 0) ? Wq : (mat == 1) ? Wk : (mat == 2) ? Wv : Wo;
    if (mat == 0) scale = 0.125f;            // fold softmax 1/sqrt(HD)
    dst = wb + (size_t)j * 0 + (size_t)(j - off) * 4 + 0;  // = wb + mat*WE
    dst = wb + ((size_t)mat << 20);          // WE = 2^20 elems
    off = off;
    i = off;                                 // reuse i as output idx within mat
    float4 v = reinterpret_cast<const float4*>(src)[off];
    ushort4 o;
    o.x = f2bf(v.x * scale); o.y = f2bf(v.y * scale);
    o.z = f2bf(v.z * scale); o.w = f2bf(v.w * scale);
    reinterpret_cast<ushort4*>(dst)[off] = o;
    return;
  }
  float4 v = reinterpret_cast<const float4*>(src)[off];
  ushort4 o;
  o.x = f2bf(v.x); o.y = f2bf(v.y); o.z = f2bf(v.z); o.w = f2bf(v.w);
  reinterpret_cast<ushort4*>(dst)[off] = o;
}

// ---------------- fused QKV GEMM: C[M,3072] = A[M,K] @ Wqkv[3072,K]^T -----
__global__ __launch_bounds__(256, 2)
void gemm_qkv(const unsigned short* __restrict__ A,
              const unsigned short* __restrict__ W,
              unsigned short* __restrict__ Out) {  // Q at 0, K at XE, Vt at 2*XE
  __shared__ __align__(16) unsigned short smem[18432];
  unsigned short* As = smem;
  unsigned short* Bs = smem + 4096;

  const int t = threadIdx.x;
  const int lane = t & 63;
  const int w = t >> 6;
  const int quad = lane >> 4;
  const int l16 = lane & 15;
  const int rowBase = blockIdx.x * 128;
  const int colBase = blockIdx.y * 128;            // 0..2944
  const int mat = colBase >> 10;
  const int nl = colBase & 1023;
  const int wr = (w >> 1) * 64;
  const int wc = (w & 1) * 64;
  const int K = DMODEL;

  f32x4_t zero4 = {0.f, 0.f, 0.f, 0.f};
  f32x4_t acc[4][4];
#pragma unroll
  for (int i = 0; i < 4; i++)
#pragma unroll
    for (int j = 0; j < 4; j++) acc[i][j] = zero4;

  const int sseg = ((t & 3) ^ ((t >> 3) & 3)) * 8;
  const unsigned short* Ag0 = A + (size_t)(rowBase + (t >> 2)) * K + sseg;
  const unsigned short* Ag1 = A + (size_t)(rowBase + 64 + (t >> 2)) * K + sseg;
  const unsigned short* Bg0 = W + (size_t)(colBase + (t >> 2)) * K + sseg;
  const unsigned short* Bg1 = W + (size_t)(colBase + 64 + (t >> 2)) * K + sseg;
  char* lA0 = (char*)As + t * 16;
  char* lA1 = (char*)As + t * 16 + 4096;
  char* lB0 = (char*)Bs + t * 16;
  char* lB1 = (char*)Bs + t * 16 + 4096;

  const int qsw = (quad ^ ((l16 >> 1) & 3)) * 8;

  for (int k0 = 0; k0 < K; k0 += 32) {
    GLDS16(Ag0 + k0, lA0);
    GLDS16(Ag1 + k0, lA1);
    GLDS16(Bg0 + k0, lB0);
    GLDS16(Bg1 + k0, lB1);
    __syncthreads();

    bf16x8_t af[4], bfr[4];
#pragma unroll
    for (int rt = 0; rt < 4; rt++)
      af[rt] = *(const bf16x8_t*)((const char*)As +
                                  ((wr + rt * 16 + l16) * 32 + qsw) * 2);
#pragma unroll
    for (int ct = 0; ct < 4; ct++)
      bfr[ct] = *(const bf16x8_t*)((const char*)Bs +
                                   ((wc + ct * 16 + l16) * 32 + qsw) * 2);
#pragma unroll
    for (int rt = 0; rt < 4; rt++)
#pragma unroll
      for (int ct = 0; ct < 4; ct++)
        acc[rt][ct] = __builtin_amdgcn_mfma_f32_16x16x32_bf16(
            af[rt], bfr[ct], acc[rt][ct], 0, 0, 0);
    __syncthreads();
  }

  const int hh = (nl + wc) >> 6;                   // head (wave-uniform)
  const int bb = rowBase >> 11;

  if (mat == 2) {
    unsigned short* T = smem + w * 4608;           // [col 64][row 72]
#pragma unroll
    for (int ct = 0; ct < 4; ct++)
#pragma unroll
      for (int rt = 0; rt < 4; rt++) {
        ushort4 pk;
        pk.x = f2bf(acc[rt][ct][0]);
        pk.y = f2bf(acc[rt][ct][1]);
        pk.z = f2bf(acc[rt][ct][2]);
        pk.w = f2bf(acc[rt][ct][3]);
        *(ushort4*)&T[(ct * 16 + l16) * 72 + rt * 16 + quad * 4] = pk;
      }
    const int srow = (rowBase & (SEQ - 1)) + wr;
    unsigned short* Cq = Out + 2 * (size_t)MROWS * DMODEL;
#pragma unroll
    for (int it = 0; it < 8; it++) {
      int nn = it * 8 + (lane >> 3);
      int sg = lane & 7;
      uint4 d = *(const uint4*)&T[nn * 72 + sg * 8];
      *(uint4*)(Cq + ((size_t)(bb * NHEAD + hh) * HDIM + nn) * SEQ + srow +
                sg * 8) = d;
    }
  } else {
    unsigned short* T = smem + w * 4608;           // [row 64][col 72]
#pragma unroll
    for (int rt = 0; rt < 4; rt++)
#pragma unroll
      for (int ct = 0; ct < 4; ct++)
#pragma unroll
        for (int r = 0; r < 4; r++)
          T[(rt * 16 + quad * 4 + r) * 72 + ct * 16 + l16] =
              f2bf(acc[rt][ct][r]);
    unsigned short* Cq = Out + (size_t)mat * MROWS * DMODEL;
#pragma unroll
    for (int it = 0; it < 8; it++) {
      int idx = it * 64 + lane;
      int row = idx >> 3, sg = idx & 7, sgx = sg ^ (row & 7);
      uint4 d = *(const uint4*)&T[row * 72 + sgx * 8];
      int m = rowBase + wr + row;
      int s = m & (SEQ - 1), b = m >> 11;
      *(uint4*)(Cq + (((size_t)(b * NHEAD + hh)) * SEQ + s) * HDIM + sgx * 8) = d;
    }
  }
}

// ---------------- out-proj GEMM: out[M,N] = ctx @ Wo^T + bias (fp32) ------
__global__ __launch_bounds__(256, 2)
void gemm_out(const unsigned short* __restrict__ A,
              const unsigned short* __restrict__ Bw,
              float* __restrict__ Cf, const float* __restrict__ bias) {
  __shared__ __align__(16) unsigned short smem[8192];
  unsigned short* As = smem;
  unsigned short* Bs = smem + 4096;
  const int t = threadIdx.x;
  const int lane = t & 63;
  const int w = t >> 6;
  const int quad = lane >> 4;
  const int l16 = lane & 15;
  const int rowBase = blockIdx.x * 128;
  const int colBase = blockIdx.y * 128;
  const int wr = (w >> 1) * 64;
  const int wc = (w & 1) * 64;
  const int K = DMODEL, N = DMODEL;

  f32x4_t zero4 = {0.f, 0.f, 0.f, 0.f};
  f32x4_t acc[4][4];
#pragma unroll
  for (int i = 0; i < 4; i++)
#pragma unroll
    for (int j = 0; j < 4; j++) acc[i][j] = zero4;

  const int sseg = ((t & 3) ^ ((t >> 3) & 3)) * 8;
  const unsigned short* Ag0 = A + (size_t)(rowBase + (t >> 2)) * K + sseg;
  const unsigned short* Ag1 = A + (size_t)(rowBase + 64 + (t >> 2)) * K + sseg;
  const unsigned short* Bg0 = Bw + (size_t)(colBase + (t >> 2)) * K + sseg;
  const unsigned short* Bg1 = Bw + (size_t)(colBase + 64 + (t >> 2)) * K + sseg;
  char* lA0 = (char*)As + t * 16;
  char* lA1 = (char*)As + t * 16 + 4096;
  char* lB0 = (char*)Bs + t * 16;
  char* lB1 = (char*)Bs + t * 16 + 4096;
  const int qsw = (quad ^ ((l16 >> 1) & 3)) * 8;

  for (int k0 = 0; k0 < K; k0 += 32) {
    GLDS16(Ag0 + k0, lA0);
    GLDS16(Ag1 + k0, lA1);
    GLDS16(Bg0 + k0, lB0);
    GLDS16(Bg1 + k0, lB1);
    __syncthreads();
    bf16x8_t af[4], bfr[4];
#pragma unroll
    for (int rt = 0; rt < 4; rt++)
      af[rt] = *(const bf16x8_t*)((const char*)As +
                                  ((wr + rt * 16 + l16) * 32 + qsw) * 2);
#pragma unroll
    for (int ct = 0; ct < 4; ct++)
      bfr[ct] = *(const bf16x8_t*)((const char*)Bs +
                                   ((wc + ct * 16 + l16) * 32 + qsw) * 2);
#pragma unroll
    for (int rt = 0; rt < 4; rt++)
#pragma unroll
      for (int ct = 0; ct < 4; ct++)
        acc[rt][ct] = __builtin_amdgcn_mfma_f32_16x16x32_bf16(
            af[rt], bfr[ct], acc[rt][ct], 0, 0, 0);
    __syncthreads();
  }

#pragma unroll
  for (int rt = 0; rt < 4; rt++)
#pragma unroll
    for (int ct = 0; ct < 4; ct++) {
      int n = colBase + wc + ct * 16 + l16;
      float bv = bias[n];
#pragma unroll
      for (int r = 0; r < 4; r++) {
        int m = rowBase + wr + rt * 16 + quad * 4 + r;
        Cf[(size_t)m * N + n] = acc[rt][ct][r] + bv;
      }
    }
}

// ---------------- causal flash attention (barrier-free, direct loads) -----
// Q,K: [B,H,S,HD]; Vt: [B,H,HD,S]. ctx: [B,S,DMODEL] bf16.
// 512 blocks; block b handles ranks {b, b^960} -> SAME bh, qt pair summing
// to 15 (34 tiles total, perfectly balanced). blockIdx ≡ bh (mod 8) keeps
// each head's K/V on one XCD's L2. No K/V LDS staging: kf/vfrag are
// A-operand fragments = 8 contiguous bf16 -> direct global bf16x8 loads,
// cached in L1/L2 (8 KB tiles, 4-wave reuse). No __syncthreads at all:
// Ps is per-wave LDS (wave-synchronous).
__global__ __launch_bounds__(256, 2)
void attn_kernel(const unsigned short* __restrict__ Qg_,
                 const unsigned short* __restrict__ Kg_,
                 const unsigned short* __restrict__ Vtg_,
                 unsigned short* __restrict__ ctx) {
  __shared__ __align__(16) unsigned short Ps[4][2048];  // per-wave, swizzled

  const int b = blockIdx.x;
  const int t = threadIdx.x;
  const int lane = t & 63, w = t >> 6;
  const int quad = lane >> 4, l16 = lane & 15;
  unsigned short* PsW = &Ps[w][0];

  const int bh = b & 63;
  const int bidx = bh >> 4, h = bh & 15;
  const size_t base = (size_t)bh * SEQ * HDIM;
  const unsigned short* KgB = Kg_ + base;
  const unsigned short* VgB = Vtg_ + base;
  const int qtI[2] = {15 - (b >> 6), b >> 6};

  f32x4_t zero4 = {0.f, 0.f, 0.f, 0.f};

#pragma unroll 1
  for (int ii = 0; ii < 2; ii++) {
    const int qt = qtI[ii];
    const int q0w = qt * 128 + w * 32;
    const int nt = 2 * qt + 2;
    const int ntw = min(nt, ((q0w + 31) >> 6) + 1);  // tiles this wave computes

    bf16x8_t qf[2][2];
#pragma unroll
    for (int q2 = 0; q2 < 2; q2++)
#pragma unroll
      for (int kh = 0; kh < 2; kh++)
        qf[q2][kh] = *(const bf16x8_t*)(Qg_ + base +
            (size_t)(q0w + q2 * 16 + l16) * HDIM + kh * 32 + quad * 8);

    float l_[2] = {0.f, 0.f};
    f32x4_t o[2][4];
#pragma unroll
    for (int q2 = 0; q2 < 2; q2++)
#pragma unroll
      for (int dt = 0; dt < 4; dt++) o[q2][dt] = zero4;

#pragma unroll 1
    for (int jt = 0; jt < ntw; ++jt) {
      // ---- direct global fragment loads (K then V; V hides behind softmax)
      const unsigned short* Kt = KgB + jt * 64 * HDIM;
      const unsigned short* Vt = VgB + jt * 64;
      bf16x8_t kf[4][2], vf[4][2];
#pragma unroll
      for (int kt = 0; kt < 4; kt++)
#pragma unroll
        for (int kh = 0; kh < 2; kh++)
          kf[kt][kh] = *(const bf16x8_t*)(Kt + (kt * 16 + l16) * HDIM +
                                          kh * 32 + quad * 8);
#pragma unroll
      for (int dt = 0; dt < 4; dt++)
#pragma unroll
        for (int kc = 0; kc < 2; kc++)
          vf[dt][kc] = *(const bf16x8_t*)(Vt + (size_t)(dt * 16 + l16) * SEQ +
                                          kc * 32 + quad * 8);

      // ---- S^T = K Q^T
      f32x4_t sc[2][4];
#pragma unroll
      for (int q2 = 0; q2 < 2; q2++)
#pragma unroll
        for (int kt = 0; kt < 4; kt++) sc[q2][kt] = zero4;
#pragma unroll
      for (int kt = 0; kt < 4; kt++)
#pragma unroll
        for (int kh = 0; kh < 2; kh++) {
          sc[0][kt] = __builtin_amdgcn_mfma_f32_16x16x32_bf16(
              kf[kt][kh], qf[0][kh], sc[0][kt], 0, 0, 0);
          sc[1][kt] = __builtin_amdgcn_mfma_f32_16x16x32_bf16(
              kf[kt][kh], qf[1][kh], sc[1][kt], 0, 0, 0);
        }

      if (jt * 64 + 63 > q0w) {  // diagonal tiles: causal mask
#pragma unroll
        for (int q2 = 0; q2 < 2; q2++) {
          int q = q0w + q2 * 16 + l16;
#pragma unroll
          for (int kt = 0; kt < 4; kt++)
#pragma unroll
            for (int r = 0; r < 4; r++) {
              int key = jt * 64 + kt * 16 + quad * 4 + r;
              if (key > q) sc[q2][kt][r] = -3.0e38f;
            }
        }
      }

      // ---- fixed-max softmax: p = exp(s); l += sum(p)
#pragma unroll
      for (int q2 = 0; q2 < 2; q2++) {
        float sum = 0.f;
#pragma unroll
        for (int kt = 0; kt < 4; kt++) {
          float p0 = __expf(sc[q2][kt][0]);
          float p1 = __expf(sc[q2][kt][1]);
          float p2 = __expf(sc[q2][kt][2]);
          float p3 = __expf(sc[q2][kt][3]);
          sum += p0 + p1 + p2 + p3;
          ushort4 pk;
          pk.x = f2bf(p0); pk.y = f2bf(p1); pk.z = f2bf(p2); pk.w = f2bf(p3);
          int u = (kt * 4 + quad) ^ ((l16 & 7) << 1);
          *(ushort4*)&PsW[q2 * 1024 + l16 * 64 + u * 4] = pk;
        }
        sum += __shfl_xor(sum, 16, 64);
        sum += __shfl_xor(sum, 32, 64);
        l_[q2] += sum;
      }

      // ---- O^T += V^T P^T
      bf16x8_t pf[2][2];
#pragma unroll
      for (int q2 = 0; q2 < 2; q2++)
#pragma unroll
        for (int kc = 0; kc < 2; kc++) {
          int u = (kc * 8 + quad * 2) ^ ((l16 & 7) << 1);
          pf[q2][kc] = *(const bf16x8_t*)&PsW[q2 * 1024 + l16 * 64 + u * 4];
        }
#pragma unroll
      for (int dt = 0; dt < 4; dt++)
#pragma unroll
        for (int kc = 0; kc < 2; kc++) {
          o[0][dt] = __builtin_amdgcn_mfma_f32_16x16x32_bf16(
              vf[dt][kc], pf[0][kc], o[0][dt], 0, 0, 0);
          o[1][dt] = __builtin_amdgcn_mfma_f32_16x16x32_bf16(
              vf[dt][kc], pf[1][kc], o[1][dt], 0, 0, 0);
        }
    }

    // ---- item epilogue: O/l -> per-wave LDS -> coalesced b128 ctx stores
#pragma unroll
    for (int q2 = 0; q2 < 2; q2++) {
      float inv = 1.0f / l_[q2];
#pragma unroll
      for (int dt = 0; dt < 4; dt++) {
        ushort4 pk;
        pk.x = f2bf(o[q2][dt][0] * inv);
        pk.y = f2bf(o[q2][dt][1] * inv);
        pk.z = f2bf(o[q2][dt][2] * inv);
        pk.w = f2bf(o[q2][dt][3] * inv);
        int u = (dt * 4 + quad) ^ ((l16 & 7) << 1);
        *(ushort4*)&PsW[q2 * 1024 + l16 * 64 + u * 4] = pk;
      }
    }
    {
      int qq = lane >> 2, sg = lane & 3;
#pragma unroll
      for (int q2 = 0; q2 < 2; q2++) {
        int ua = (sg * 2) ^ ((qq & 7) << 1);
        int ub = (sg * 2 + 8) ^ ((qq & 7) << 1);
        uint4 da = *(const uint4*)&PsW[q2 * 1024 + qq * 64 + ua * 4];
        uint4 db = *(const uint4*)&PsW[q2 * 1024 + qq * 64 + ub * 4];
        size_t rowoff =
            ((size_t)(bidx * SEQ + q0w + q2 * 16 + qq)) * DMODEL + h * HDIM;
        *(uint4*)(ctx + rowoff + sg * 8) = da;
        *(uint4*)(ctx + rowoff + (sg + 4) * 8) = db;
      }
    }
  }
}

// ---------------- launch ----------------
extern "C" void kernel_launch(void* const* d_in, const int* in_sizes, int n_in,
                              void* d_out, int out_size, void* d_ws,
                              size_t ws_size, hipStream_t stream) {
  const float* x  = (const float*)d_in[0];
  const float* Wq = (const float*)d_in[1];
  const float* Wk = (const float*)d_in[2];
  const float* Wv = (const float*)d_in[3];
  const float* Wo = (const float*)d_in[4];
  const float* bo = (const float*)d_in[5];
  float* out = (float*)d_out;

  const size_t XE = (size_t)MROWS * DMODEL;
  const size_t WE = (size_t)DMODEL * DMODEL;

  unsigned short* xb   = (unsigned short*)d_ws;
  unsigned short* wqb  = xb + XE;        // wq|wk|wv|wo contiguous
  unsigned short* wob  = wqb + 3 * WE;
  unsigned short* Qb   = wqb + 4 * WE;   // Q|K|Vt contiguous
  unsigned short* Kb   = Qb + XE;
  unsigned short* Vtb  = Kb + XE;
  unsigned short* ctxb = xb;             // x dead after QKV GEMM

  cast_all<<<(XE4 + 4 * WE4 + 255) / 256, 256, 0, stream>>>(x, Wq, Wk, Wv, Wo,
                                                            xb, wqb);

  gemm_qkv<<<dim3(MROWS / 128, 3 * DMODEL / 128), 256, 0, stream>>>(xb, wqb, Qb);

  attn_kernel<<<dim3(512), 256, 0, stream>>>(Qb, Kb, Vtb, ctxb);

  gemm_out<<<dim3(MROWS / 128, DMODEL / 128), 256, 0, stream>>>(ctxb, wob, out, bo);
}

// Round 6
// 252.266 us; speedup vs baseline: 1.1971x; 1.1971x over previous
//
#include <hip/hip_runtime.h>
#include <hip/hip_bf16.h>
#include <stdint.h>

#define B_N 4
#define SEQ 2048
#define DMODEL 1024
#define NHEAD 16
#define HDIM 64
#define BHEADS (B_N * NHEAD)     // 64
#define MROWS (B_N * SEQ)        // 8192

typedef short bf16x8_t __attribute__((ext_vector_type(8)));
typedef float f32x4_t __attribute__((ext_vector_type(4)));

static __device__ __forceinline__ unsigned short f2bf(float f) {
  __hip_bfloat16 h = __float2bfloat16(f);
  return __builtin_bit_cast(unsigned short, h);
}

#define GLDS16(gp, lp)                                                        \
  __builtin_amdgcn_global_load_lds(                                           \
      (const __attribute__((address_space(1))) unsigned int*)(gp),            \
      (__attribute__((address_space(3))) unsigned int*)(lp), 16, 0, 0)

// ---------------- fused fp32 -> bf16 cast (x + all 4 weights) -------------
#define XE4 2097152   // MROWS*DMODEL/4
#define WE4 262144    // DMODEL*DMODEL/4
__global__ void cast_all(const float* __restrict__ x,
                         const float* __restrict__ Wq,
                         const float* __restrict__ Wk,
                         const float* __restrict__ Wv,
                         const float* __restrict__ Wo,
                         unsigned short* __restrict__ xb,
                         unsigned short* __restrict__ wb) {
  int i = blockIdx.x * blockDim.x + threadIdx.x;
  if (i < XE4) {
    float4 v = reinterpret_cast<const float4*>(x)[i];
    ushort4 o;
    o.x = f2bf(v.x); o.y = f2bf(v.y); o.z = f2bf(v.z); o.w = f2bf(v.w);
    reinterpret_cast<ushort4*>(xb)[i] = o;
  } else {
    int j = i - XE4;
    int mat = j >> 18;                       // WE4 = 2^18
    int off = j & (WE4 - 1);
    const float* src = (mat == 0) ? Wq : (mat == 1) ? Wk
                       : (mat == 2) ? Wv : Wo;
    float scale = (mat == 0) ? 0.125f : 1.0f;  // fold softmax 1/sqrt(HD)
    unsigned short* dst = wb + ((size_t)mat << 20);  // WE = 2^20 elems
    float4 v = reinterpret_cast<const float4*>(src)[off];
    ushort4 o;
    o.x = f2bf(v.x * scale); o.y = f2bf(v.y * scale);
    o.z = f2bf(v.z * scale); o.w = f2bf(v.w * scale);
    reinterpret_cast<ushort4*>(dst)[off] = o;
  }
}

// ---------------- fused QKV GEMM: C[M,3072] = A[M,K] @ Wqkv[3072,K]^T -----
__global__ __launch_bounds__(256, 2)
void gemm_qkv(const unsigned short* __restrict__ A,
              const unsigned short* __restrict__ W,
              unsigned short* __restrict__ Out) {  // Q at 0, K at XE, Vt at 2*XE
  __shared__ __align__(16) unsigned short smem[18432];
  unsigned short* As = smem;
  unsigned short* Bs = smem + 4096;

  const int t = threadIdx.x;
  const int lane = t & 63;
  const int w = t >> 6;
  const int quad = lane >> 4;
  const int l16 = lane & 15;
  const int rowBase = blockIdx.x * 128;
  const int colBase = blockIdx.y * 128;            // 0..2944
  const int mat = colBase >> 10;
  const int nl = colBase & 1023;
  const int wr = (w >> 1) * 64;
  const int wc = (w & 1) * 64;
  const int K = DMODEL;

  f32x4_t zero4 = {0.f, 0.f, 0.f, 0.f};
  f32x4_t acc[4][4];
#pragma unroll
  for (int i = 0; i < 4; i++)
#pragma unroll
    for (int j = 0; j < 4; j++) acc[i][j] = zero4;

  const int sseg = ((t & 3) ^ ((t >> 3) & 3)) * 8;
  const unsigned short* Ag0 = A + (size_t)(rowBase + (t >> 2)) * K + sseg;
  const unsigned short* Ag1 = A + (size_t)(rowBase + 64 + (t >> 2)) * K + sseg;
  const unsigned short* Bg0 = W + (size_t)(colBase + (t >> 2)) * K + sseg;
  const unsigned short* Bg1 = W + (size_t)(colBase + 64 + (t >> 2)) * K + sseg;
  char* lA0 = (char*)As + t * 16;
  char* lA1 = (char*)As + t * 16 + 4096;
  char* lB0 = (char*)Bs + t * 16;
  char* lB1 = (char*)Bs + t * 16 + 4096;

  const int qsw = (quad ^ ((l16 >> 1) & 3)) * 8;

  for (int k0 = 0; k0 < K; k0 += 32) {
    GLDS16(Ag0 + k0, lA0);
    GLDS16(Ag1 + k0, lA1);
    GLDS16(Bg0 + k0, lB0);
    GLDS16(Bg1 + k0, lB1);
    __syncthreads();

    bf16x8_t af[4], bfr[4];
#pragma unroll
    for (int rt = 0; rt < 4; rt++)
      af[rt] = *(const bf16x8_t*)((const char*)As +
                                  ((wr + rt * 16 + l16) * 32 + qsw) * 2);
#pragma unroll
    for (int ct = 0; ct < 4; ct++)
      bfr[ct] = *(const bf16x8_t*)((const char*)Bs +
                                   ((wc + ct * 16 + l16) * 32 + qsw) * 2);
#pragma unroll
    for (int rt = 0; rt < 4; rt++)
#pragma unroll
      for (int ct = 0; ct < 4; ct++)
        acc[rt][ct] = __builtin_amdgcn_mfma_f32_16x16x32_bf16(
            af[rt], bfr[ct], acc[rt][ct], 0, 0, 0);
    __syncthreads();
  }

  const int hh = (nl + wc) >> 6;                   // head (wave-uniform)
  const int bb = rowBase >> 11;

  if (mat == 2) {
    unsigned short* T = smem + w * 4608;           // [col 64][row 72]
#pragma unroll
    for (int ct = 0; ct < 4; ct++)
#pragma unroll
      for (int rt = 0; rt < 4; rt++) {
        ushort4 pk;
        pk.x = f2bf(acc[rt][ct][0]);
        pk.y = f2bf(acc[rt][ct][1]);
        pk.z = f2bf(acc[rt][ct][2]);
        pk.w = f2bf(acc[rt][ct][3]);
        *(ushort4*)&T[(ct * 16 + l16) * 72 + rt * 16 + quad * 4] = pk;
      }
    const int srow = (rowBase & (SEQ - 1)) + wr;
    unsigned short* Cq = Out + 2 * (size_t)MROWS * DMODEL;
#pragma unroll
    for (int it = 0; it < 8; it++) {
      int nn = it * 8 + (lane >> 3);
      int sg = lane & 7;
      uint4 d = *(const uint4*)&T[nn * 72 + sg * 8];
      *(uint4*)(Cq + ((size_t)(bb * NHEAD + hh) * HDIM + nn) * SEQ + srow +
                sg * 8) = d;
    }
  } else {
    unsigned short* T = smem + w * 4608;           // [row 64][col 72]
#pragma unroll
    for (int rt = 0; rt < 4; rt++)
#pragma unroll
      for (int ct = 0; ct < 4; ct++)
#pragma unroll
        for (int r = 0; r < 4; r++)
          T[(rt * 16 + quad * 4 + r) * 72 + ct * 16 + l16] =
              f2bf(acc[rt][ct][r]);
    unsigned short* Cq = Out + (size_t)mat * MROWS * DMODEL;
#pragma unroll
    for (int it = 0; it < 8; it++) {
      int idx = it * 64 + lane;
      int row = idx >> 3, sg = idx & 7, sgx = sg ^ (row & 7);
      uint4 d = *(const uint4*)&T[row * 72 + sgx * 8];
      int m = rowBase + wr + row;
      int s = m & (SEQ - 1), b = m >> 11;
      *(uint4*)(Cq + (((size_t)(b * NHEAD + hh)) * SEQ + s) * HDIM + sgx * 8) = d;
    }
  }
}

// ---------------- out-proj GEMM: out[M,N] = ctx @ Wo^T + bias (fp32) ------
__global__ __launch_bounds__(256, 2)
void gemm_out(const unsigned short* __restrict__ A,
              const unsigned short* __restrict__ Bw,
              float* __restrict__ Cf, const float* __restrict__ bias) {
  __shared__ __align__(16) unsigned short smem[8192];
  unsigned short* As = smem;
  unsigned short* Bs = smem + 4096;
  const int t = threadIdx.x;
  const int lane = t & 63;
  const int w = t >> 6;
  const int quad = lane >> 4;
  const int l16 = lane & 15;
  const int rowBase = blockIdx.x * 128;
  const int colBase = blockIdx.y * 128;
  const int wr = (w >> 1) * 64;
  const int wc = (w & 1) * 64;
  const int K = DMODEL, N = DMODEL;

  f32x4_t zero4 = {0.f, 0.f, 0.f, 0.f};
  f32x4_t acc[4][4];
#pragma unroll
  for (int i = 0; i < 4; i++)
#pragma unroll
    for (int j = 0; j < 4; j++) acc[i][j] = zero4;

  const int sseg = ((t & 3) ^ ((t >> 3) & 3)) * 8;
  const unsigned short* Ag0 = A + (size_t)(rowBase + (t >> 2)) * K + sseg;
  const unsigned short* Ag1 = A + (size_t)(rowBase + 64 + (t >> 2)) * K + sseg;
  const unsigned short* Bg0 = Bw + (size_t)(colBase + (t >> 2)) * K + sseg;
  const unsigned short* Bg1 = Bw + (size_t)(colBase + 64 + (t >> 2)) * K + sseg;
  char* lA0 = (char*)As + t * 16;
  char* lA1 = (char*)As + t * 16 + 4096;
  char* lB0 = (char*)Bs + t * 16;
  char* lB1 = (char*)Bs + t * 16 + 4096;
  const int qsw = (quad ^ ((l16 >> 1) & 3)) * 8;

  for (int k0 = 0; k0 < K; k0 += 32) {
    GLDS16(Ag0 + k0, lA0);
    GLDS16(Ag1 + k0, lA1);
    GLDS16(Bg0 + k0, lB0);
    GLDS16(Bg1 + k0, lB1);
    __syncthreads();
    bf16x8_t af[4], bfr[4];
#pragma unroll
    for (int rt = 0; rt < 4; rt++)
      af[rt] = *(const bf16x8_t*)((const char*)As +
                                  ((wr + rt * 16 + l16) * 32 + qsw) * 2);
#pragma unroll
    for (int ct = 0; ct < 4; ct++)
      bfr[ct] = *(const bf16x8_t*)((const char*)Bs +
                                   ((wc + ct * 16 + l16) * 32 + qsw) * 2);
#pragma unroll
    for (int rt = 0; rt < 4; rt++)
#pragma unroll
      for (int ct = 0; ct < 4; ct++)
        acc[rt][ct] = __builtin_amdgcn_mfma_f32_16x16x32_bf16(
            af[rt], bfr[ct], acc[rt][ct], 0, 0, 0);
    __syncthreads();
  }

#pragma unroll
  for (int rt = 0; rt < 4; rt++)
#pragma unroll
    for (int ct = 0; ct < 4; ct++) {
      int n = colBase + wc + ct * 16 + l16;
      float bv = bias[n];
#pragma unroll
      for (int r = 0; r < 4; r++) {
        int m = rowBase + wr + rt * 16 + quad * 4 + r;
        Cf[(size_t)m * N + n] = acc[rt][ct][r] + bv;
      }
    }
}

// ---------------- causal flash attention (256-q tile, LDS dbuf) -----------
// Q,K: [B,H,S,HD]; Vt: [B,H,HD,S]. ctx: [B,S,DMODEL] bf16.
// 512 items = (8 qt x 64 bh), one per block; q-tile 256 rows, 64 rows/wave
// (q2 in 0..3). Ordering: b<256 -> qt=7-(b>>6); else qt=(b-256)>>6 -> the
// offset-256 block pair (same CU slot under 8-XCD round-robin) sums to 36
// tiles AND shares bh (L1/L2 K/V reuse). kf/vf LDS reads amortize over 2x
// queries vs the 128-q tile -> ~1.5x less LDS-read per unit work.
__global__ __launch_bounds__(256, 2)
void attn_kernel(const unsigned short* __restrict__ Qg_,
                 const unsigned short* __restrict__ Kg_,
                 const unsigned short* __restrict__ Vtg_,
                 unsigned short* __restrict__ ctx) {
  __shared__ __align__(16) unsigned short Ks[2][4096];
  __shared__ __align__(16) unsigned short Vs[2][4096];
  __shared__ __align__(16) unsigned short Ps[4][4096];  // per-wave, swizzled

  const int b = blockIdx.x;
  const int t = threadIdx.x;
  const int lane = t & 63, w = t >> 6;
  const int quad = lane >> 4, l16 = lane & 15;
  const int sw = l16 & 7;
  unsigned short* PsW = &Ps[w][0];

  const int qt = (b < 256) ? (7 - (b >> 6)) : ((b - 256) >> 6);
  const int bh = b & 63;
  const int bidx = bh >> 4, h = bh & 15;
  const size_t base = (size_t)bh * SEQ * HDIM;
  const unsigned short* KgB = Kg_ + base;
  const unsigned short* VgB = Vtg_ + base;
  const int nt = 4 * qt + 4;
  const int q0w = qt * 256 + w * 64;

  // Q fragments for 64 q-rows: loop-invariant, direct global->reg
  bf16x8_t qf[4][2];
#pragma unroll
  for (int q2 = 0; q2 < 4; q2++)
#pragma unroll
    for (int kh = 0; kh < 2; kh++)
      qf[q2][kh] = *(const bf16x8_t*)(Qg_ + base +
          (size_t)(q0w + q2 * 16 + l16) * HDIM + kh * 32 + quad * 8);

  float l_[4] = {0.f, 0.f, 0.f, 0.f};
  f32x4_t zero4 = {0.f, 0.f, 0.f, 0.f};
  f32x4_t o[4][4];
#pragma unroll
  for (int q2 = 0; q2 < 4; q2++)
#pragma unroll
    for (int dt = 0; dt < 4; dt++) o[q2][dt] = zero4;

  const int r0 = t >> 3;
  const int s0 = ((t & 7) ^ (r0 & 7)) * 8;
  const int r1 = r0 + 32;

  // prologue: stage tile 0 into buf 0
  GLDS16(KgB + r0 * HDIM + s0, (char*)&Ks[0][0] + t * 16);
  GLDS16(KgB + r1 * HDIM + s0, (char*)&Ks[0][0] + t * 16 + 4096);
  GLDS16(VgB + (size_t)r0 * SEQ + s0, (char*)&Vs[0][0] + t * 16);
  GLDS16(VgB + (size_t)r1 * SEQ + s0, (char*)&Vs[0][0] + t * 16 + 4096);

  for (int jt = 0; jt < nt; ++jt) {
    const int buf = jt & 1;
    __syncthreads();  // tile-jt loads drained; all waves done with buf^1
    if (jt + 1 < nt) {  // prefetch next tile into other buffer
      const unsigned short* Kg = KgB + (size_t)(jt + 1) * 64 * HDIM;
      const unsigned short* Vg = VgB + (jt + 1) * 64;
      char* kd = (char*)&Ks[buf ^ 1][0] + t * 16;
      char* vd = (char*)&Vs[buf ^ 1][0] + t * 16;
      GLDS16(Kg + r0 * HDIM + s0, kd);
      GLDS16(Kg + r1 * HDIM + s0, kd + 4096);
      GLDS16(Vg + (size_t)r0 * SEQ + s0, vd);
      GLDS16(Vg + (size_t)r1 * SEQ + s0, vd + 4096);
    }

    if (jt * 64 <= q0w + 63) {  // skip fully-future tiles (wave-uniform)
      const unsigned short* Kb = &Ks[buf][0];
      const unsigned short* Vb = &Vs[buf][0];
      const bool needmask = (jt * 64 + 63 > q0w);

      bf16x8_t kf[4][2];
#pragma unroll
      for (int kt = 0; kt < 4; kt++)
#pragma unroll
        for (int kh = 0; kh < 2; kh++)
          kf[kt][kh] = *(const bf16x8_t*)((const char*)Kb +
              ((kt * 16 + l16) * 64 + (((kh * 4 + quad) ^ sw) * 8)) * 2);

      // per-q2: S^T MFMAs -> mask -> exp/sum -> Ps write (wave-synchronous)
#pragma unroll
      for (int q2 = 0; q2 < 4; q2++) {
        f32x4_t sc[4];
#pragma unroll
        for (int kt = 0; kt < 4; kt++) sc[kt] = zero4;
#pragma unroll
        for (int kt = 0; kt < 4; kt++)
#pragma unroll
          for (int kh = 0; kh < 2; kh++)
            sc[kt] = __builtin_amdgcn_mfma_f32_16x16x32_bf16(
                kf[kt][kh], qf[q2][kh], sc[kt], 0, 0, 0);

        if (needmask) {
          int q = q0w + q2 * 16 + l16;
#pragma unroll
          for (int kt = 0; kt < 4; kt++)
#pragma unroll
            for (int r = 0; r < 4; r++) {
              int key = jt * 64 + kt * 16 + quad * 4 + r;
              if (key > q) sc[kt][r] = -3.0e38f;
            }
        }

        float sum = 0.f;
#pragma unroll
        for (int kt = 0; kt < 4; kt++) {
          float p0 = __expf(sc[kt][0]);
          float p1 = __expf(sc[kt][1]);
          float p2 = __expf(sc[kt][2]);
          float p3 = __expf(sc[kt][3]);
          sum += p0 + p1 + p2 + p3;
          ushort4 pk;
          pk.x = f2bf(p0); pk.y = f2bf(p1); pk.z = f2bf(p2); pk.w = f2bf(p3);
          int u = (kt * 4 + quad) ^ ((l16 & 7) << 1);
          *(ushort4*)&PsW[q2 * 1024 + l16 * 64 + u * 4] = pk;
        }
        sum += __shfl_xor(sum, 16, 64);
        sum += __shfl_xor(sum, 32, 64);
        l_[q2] += sum;
      }

      // PV: O^T += V^T P^T
      bf16x8_t vf[4][2];
#pragma unroll
      for (int dt = 0; dt < 4; dt++)
#pragma unroll
        for (int kc = 0; kc < 2; kc++)
          vf[dt][kc] = *(const bf16x8_t*)((const char*)Vb +
              ((dt * 16 + l16) * 64 + (((kc * 4 + quad) ^ sw) * 8)) * 2);
#pragma unroll
      for (int q2 = 0; q2 < 4; q2++) {
        bf16x8_t pf[2];
#pragma unroll
        for (int kc = 0; kc < 2; kc++) {
          int u = (kc * 8 + quad * 2) ^ ((l16 & 7) << 1);
          pf[kc] = *(const bf16x8_t*)&PsW[q2 * 1024 + l16 * 64 + u * 4];
        }
#pragma unroll
        for (int dt = 0; dt < 4; dt++)
#pragma unroll
          for (int kc = 0; kc < 2; kc++)
            o[q2][dt] = __builtin_amdgcn_mfma_f32_16x16x32_bf16(
                vf[dt][kc], pf[kc], o[q2][dt], 0, 0, 0);
      }
    }
  }

  // epilogue: O/l -> per-wave LDS (swizzled) -> coalesced b128 ctx stores
#pragma unroll
  for (int q2 = 0; q2 < 4; q2++) {
    float inv = 1.0f / l_[q2];
#pragma unroll
    for (int dt = 0; dt < 4; dt++) {
      ushort4 pk;
      pk.x = f2bf(o[q2][dt][0] * inv);
      pk.y = f2bf(o[q2][dt][1] * inv);
      pk.z = f2bf(o[q2][dt][2] * inv);
      pk.w = f2bf(o[q2][dt][3] * inv);
      int u = (dt * 4 + quad) ^ ((l16 & 7) << 1);
      *(ushort4*)&PsW[q2 * 1024 + l16 * 64 + u * 4] = pk;
    }
  }
  {
    int qq = lane >> 2, sg = lane & 3;
#pragma unroll
    for (int q2 = 0; q2 < 4; q2++) {
      int ua = (sg * 2) ^ ((qq & 7) << 1);
      int ub = (sg * 2 + 8) ^ ((qq & 7) << 1);
      uint4 da = *(const uint4*)&PsW[q2 * 1024 + qq * 64 + ua * 4];
      uint4 db = *(const uint4*)&PsW[q2 * 1024 + qq * 64 + ub * 4];
      size_t rowoff =
          ((size_t)(bidx * SEQ + q0w + q2 * 16 + qq)) * DMODEL + h * HDIM;
      *(uint4*)(ctx + rowoff + sg * 8) = da;
      *(uint4*)(ctx + rowoff + (sg + 4) * 8) = db;
    }
  }
}

// ---------------- launch ----------------
extern "C" void kernel_launch(void* const* d_in, const int* in_sizes, int n_in,
                              void* d_out, int out_size, void* d_ws,
                              size_t ws_size, hipStream_t stream) {
  const float* x  = (const float*)d_in[0];
  const float* Wq = (const float*)d_in[1];
  const float* Wk = (const float*)d_in[2];
  const float* Wv = (const float*)d_in[3];
  const float* Wo = (const float*)d_in[4];
  const float* bo = (const float*)d_in[5];
  float* out = (float*)d_out;

  const size_t XE = (size_t)MROWS * DMODEL;
  const size_t WE = (size_t)DMODEL * DMODEL;

  unsigned short* xb   = (unsigned short*)d_ws;
  unsigned short* wqb  = xb + XE;        // wq|wk|wv|wo contiguous
  unsigned short* wob  = wqb + 3 * WE;
  unsigned short* Qb   = wqb + 4 * WE;   // Q|K|Vt contiguous
  unsigned short* Kb   = Qb + XE;
  unsigned short* Vtb  = Kb + XE;
  unsigned short* ctxb = xb;             // x dead after QKV GEMM

  cast_all<<<(XE4 + 4 * WE4 + 255) / 256, 256, 0, stream>>>(x, Wq, Wk, Wv, Wo,
                                                            xb, wqb);

  gemm_qkv<<<dim3(MROWS / 128, 3 * DMODEL / 128), 256, 0, stream>>>(xb, wqb, Qb);

  attn_kernel<<<dim3(512), 256, 0, stream>>>(Qb, Kb, Vtb, ctxb);

  gemm_out<<<dim3(MROWS / 128, DMODEL / 128), 256, 0, stream>>>(ctxb, wob, out, bo);
}